// Round 2
// baseline (734.014 us; speedup 1.0000x reference)
//
#include <hip/hip_runtime.h>
#include <math.h>

#define BB   4096
#define SS   5
#define DD   64
#define HSZ  961
#define VSA  1024
#define NT   256
#define NB   2      // batches per block (NB=4 spilled: 190-reg live set @128 cap)
#define LNE  1e-3f

// padded h layout: P[r] = h[r-POFF] for r in [POFF, POFF+960], else 0
#define POFF 64
#define PW   1092   // max index accessed = 1091; rows 16B-aligned

typedef float v4f __attribute__((ext_vector_type(4)));   // native vec for nontemporal

__device__ __forceinline__ float silu_f(float x) { return x / (1.f + __expf(-x)); }

// ---- DPP wave64 sum: pure-VALU reduction, no lgkmcnt traffic ----
// (replaces __shfl_down chains: ds_bpermute shares lgkmcnt with s_load/SMEM,
//  so every shuffle wait was draining the scalar-load pipeline too)
// ctrl must be an immediate -> template parameter (clang checks pre-inline)
template <int CTRL>
__device__ __forceinline__ float dpp_add(float x) {
    int t = __builtin_amdgcn_update_dpp(0, __builtin_bit_cast(int, x),
                                        CTRL, 0xf, 0xf, false);
    return x + __builtin_bit_cast(float, t);
}
// full 64-lane sum; valid in lane 63
__device__ __forceinline__ float wave64_sum_l63(float x) {
    x = dpp_add<0x111>(x);  // row_shr:1
    x = dpp_add<0x112>(x);  // row_shr:2
    x = dpp_add<0x114>(x);  // row_shr:4
    x = dpp_add<0x118>(x);  // row_shr:8
    x = dpp_add<0x142>(x);  // row_bcast:15
    x = dpp_add<0x143>(x);  // row_bcast:31
    return x;
}

// ---- Kernel 1: sp = LN(silu(conv(symbols,h))); also emit zero-padded h ----
__global__ __launch_bounds__(NT)
void sp_kernel(const float* __restrict__ symbols, const float* __restrict__ h,
               const float* __restrict__ gamma, const float* __restrict__ beta,
               float* __restrict__ sp, float* __restrict__ hpadG)
{
    __shared__ float hpad[PW];
    __shared__ float red[4][2];
    const int s = blockIdx.x;
    const int tid = threadIdx.x;
    const int lane = tid & 63, wave = tid >> 6;

    for (int r = tid; r < PW; r += NT) {
        const float v = (r >= POFF && r <= POFF + 960) ? h[s * HSZ + (r - POFF)] : 0.f;
        hpad[r] = v;
        hpadG[s * PW + r] = v;        // padded copy for main_kernel
    }
    __syncthreads();

    const int base = 1020 - 4 * tid;
    float hw[8];
    *(float4*)&hw[0] = *(const float4*)&hpad[base];
    float acc[4] = {0.f, 0.f, 0.f, 0.f};
    const float* xp = symbols + s * DD;
#pragma unroll
    for (int c = 0; c < 16; c++) {
        *(float4*)&hw[4] = *(const float4*)&hpad[base + 4 * (c + 1)];
        const float x0 = xp[4 * c + 0];
        const float x1 = xp[4 * c + 1];
        const float x2 = xp[4 * c + 2];
        const float x3 = xp[4 * c + 3];
        acc[0] += x0 * hw[4]; acc[0] += x1 * hw[5]; acc[0] += x2 * hw[6]; acc[0] += x3 * hw[7];
        acc[1] += x0 * hw[3]; acc[1] += x1 * hw[4]; acc[1] += x2 * hw[5]; acc[1] += x3 * hw[6];
        acc[2] += x0 * hw[2]; acc[2] += x1 * hw[3]; acc[2] += x2 * hw[4]; acc[2] += x3 * hw[5];
        acc[3] += x0 * hw[1]; acc[3] += x1 * hw[2]; acc[3] += x2 * hw[3]; acc[3] += x3 * hw[4];
        hw[0] = hw[4]; hw[1] = hw[5]; hw[2] = hw[6]; hw[3] = hw[7];
    }

    float ys[4];
    float lsum = 0.f, lsq = 0.f;
#pragma unroll
    for (int j = 0; j < 4; j++) {
        ys[j] = silu_f(acc[j]);
        lsum += ys[j]; lsq += ys[j] * ys[j];
    }
    lsum = wave64_sum_l63(lsum);
    lsq  = wave64_sum_l63(lsq);
    if (lane == 63) { red[wave][0] = lsum; red[wave][1] = lsq; }
    __syncthreads();
    float s0 = 0.f, s1 = 0.f;
#pragma unroll
    for (int w = 0; w < 4; w++) { s0 += red[w][0]; s1 += red[w][1]; }
    const float mean = s0 * (1.f / VSA);
    const float rstd = rsqrtf(s1 * (1.f / VSA) - mean * mean + LNE);

    const float4 g4 = *(const float4*)&gamma[4 * tid];
    const float4 b4 = *(const float4*)&beta[4 * tid];
    float4 o;
    o.x = (ys[0] - mean) * rstd * g4.x + b4.x;
    o.y = (ys[1] - mean) * rstd * g4.y + b4.y;
    o.z = (ys[2] - mean) * rstd * g4.z + b4.z;
    o.w = (ys[3] - mean) * rstd * g4.w + b4.w;
    *(float4*)&sp[s * VSA + 4 * tid] = o;
}

// ------- Kernel 2: NB=2 batches per block --------------------------------
// values staged in LDS (uniform ds_read broadcast, in-order lgkm) instead of
// the s_load path: SMEM returns out-of-order, so every consume forced a full
// lgkmcnt(0) drain (~80 drains/wave interleaved with the shuffle DS chains).
__global__ __launch_bounds__(NT, 4)
void main_kernel(const float* __restrict__ values, const float* __restrict__ hpadG,
                 const float* __restrict__ sp, const float* __restrict__ gamma,
                 const float* __restrict__ beta, float* __restrict__ out)
{
    __shared__ __align__(16) float xs[NB][SS][DD];   // 2.5 KB block's values
    __shared__ float red[SS][NB][4][2];
    __shared__ int   scorered[NB][4][SS * SS];
    __shared__ float wbuf[NB][SS * SS];

    const int tid = threadIdx.x;
    const int lane = tid & 63, wave = tid >> 6;
    const int b0 = blockIdx.x * NB;
    const int base = 1020 - 4 * tid;

    // stage NB*5*64 = 640 contiguous floats, coalesced
    if (tid < (NB * SS * DD) / 4) {
        ((float4*)xs)[tid] =
            ((const float4*)(values + (size_t)b0 * (SS * DD)))[tid];
    }
    __syncthreads();

    float vp[NB][SS][4];   // conv->silu->LN results, t = 4*tid+j

    // conv + silu for all 5 s x NB batches; h window loaded once per (s,chunk)
#pragma unroll
    for (int s = 0; s < SS; s++) {
        const float* hp = hpadG + s * PW + base;
        float hw[8];
        *(float4*)&hw[0] = *(const float4*)hp;
        float acc[NB][4];
#pragma unroll
        for (int nb = 0; nb < NB; nb++)
            acc[nb][0] = acc[nb][1] = acc[nb][2] = acc[nb][3] = 0.f;
#pragma unroll
        for (int c = 0; c < 16; c++) {
            *(float4*)&hw[4] = *(const float4*)(hp + 4 * (c + 1));
#pragma unroll
            for (int nb = 0; nb < NB; nb++) {
                // uniform LDS broadcast read; in-order lgkm -> pipelines
                const float4 xv = *(const float4*)&xs[nb][s][4 * c];
                acc[nb][0] += xv.x * hw[4]; acc[nb][0] += xv.y * hw[5]; acc[nb][0] += xv.z * hw[6]; acc[nb][0] += xv.w * hw[7];
                acc[nb][1] += xv.x * hw[3]; acc[nb][1] += xv.y * hw[4]; acc[nb][1] += xv.z * hw[5]; acc[nb][1] += xv.w * hw[6];
                acc[nb][2] += xv.x * hw[2]; acc[nb][2] += xv.y * hw[3]; acc[nb][2] += xv.z * hw[4]; acc[nb][2] += xv.w * hw[5];
                acc[nb][3] += xv.x * hw[1]; acc[nb][3] += xv.y * hw[2]; acc[nb][3] += xv.z * hw[3]; acc[nb][3] += xv.w * hw[4];
            }
            hw[0] = hw[4]; hw[1] = hw[5]; hw[2] = hw[6]; hw[3] = hw[7];
        }
        // silu + LN partials per batch (pure-VALU DPP reduce)
#pragma unroll
        for (int nb = 0; nb < NB; nb++) {
            float lsum = 0.f, lsq = 0.f;
#pragma unroll
            for (int j = 0; j < 4; j++) {
                const float y = silu_f(acc[nb][j]);
                vp[nb][s][j] = y; lsum += y; lsq += y * y;
            }
            lsum = wave64_sum_l63(lsum);
            lsq  = wave64_sum_l63(lsq);
            if (lane == 63) { red[s][nb][wave][0] = lsum; red[s][nb][wave][1] = lsq; }
        }
    }
    __syncthreads();

    // LayerNorm epilogue in registers
    const float4 g4 = *(const float4*)&gamma[4 * tid];
    const float4 b4 = *(const float4*)&beta[4 * tid];
#pragma unroll
    for (int s = 0; s < SS; s++) {
#pragma unroll
        for (int nb = 0; nb < NB; nb++) {
            float s0 = 0.f, s1 = 0.f;
#pragma unroll
            for (int w = 0; w < 4; w++) { s0 += red[s][nb][w][0]; s1 += red[s][nb][w][1]; }
            const float mean = s0 * (1.f / VSA);
            const float rstd = rsqrtf(s1 * (1.f / VSA) - mean * mean + LNE);
            vp[nb][s][0] = (vp[nb][s][0] - mean) * rstd * g4.x + b4.x;
            vp[nb][s][1] = (vp[nb][s][1] - mean) * rstd * g4.y + b4.y;
            vp[nb][s][2] = (vp[nb][s][2] - mean) * rstd * g4.z + b4.z;
            vp[nb][s][3] = (vp[nb][s][3] - mean) * rstd * g4.w + b4.w;
        }
    }

    // sp fragments (batch-independent, L1/L2-hot)
    float sp4[SS][4];
#pragma unroll
    for (int i = 0; i < SS; i++)
        *(float4*)&sp4[i][0] = *(const float4*)&sp[i * VSA + 4 * tid];

    // scores via ballot: sign(a)*sign(b) = 1 - 2*[signbits differ]
#pragma unroll
    for (int nb = 0; nb < NB; nb++) {
        int neq[SS * SS];
#pragma unroll
        for (int p = 0; p < SS * SS; p++) neq[p] = 0;
#pragma unroll
        for (int jj = 0; jj < 4; jj++) {
            unsigned long long bvi[SS];
#pragma unroll
            for (int i = 0; i < SS; i++) bvi[i] = __ballot(vp[nb][i][jj] > 0.f);
#pragma unroll
            for (int j = 0; j < SS; j++) {
                const float sjv = sp4[j][jj];
#pragma unroll
                for (int i = 0; i < SS; i++) {
                    const unsigned long long bs = __ballot(vp[nb][i][jj] + sjv > 0.f);
                    neq[j * SS + i] += (int)__popcll(bvi[i] ^ bs);
                }
            }
        }
        if (lane == 0) {
#pragma unroll
            for (int p = 0; p < SS * SS; p++) scorered[nb][wave][p] = neq[p];
        }
    }
    __syncthreads();

    // softmax over i per (nb, j) — NB*SS threads
    if (tid < NB * SS) {
        const int nb = tid / SS, j = tid - nb * SS;
        float sc[SS];
#pragma unroll
        for (int i = 0; i < SS; i++) {
            const int nq = scorered[nb][0][j * SS + i] + scorered[nb][1][j * SS + i]
                         + scorered[nb][2][j * SS + i] + scorered[nb][3][j * SS + i];
            sc[i] = 1.f - (2.f / VSA) * (float)nq;
        }
        float m = sc[0];
#pragma unroll
        for (int i = 1; i < SS; i++) m = fmaxf(m, sc[i]);
        float e[SS], ssum = 0.f;
#pragma unroll
        for (int i = 0; i < SS; i++) { e[i] = __expf(sc[i] - m); ssum += e[i]; }
        const float inv = 1.f / ssum;
#pragma unroll
        for (int i = 0; i < SS; i++) wbuf[nb][j * SS + i] = e[i] * inv;
    }
    __syncthreads();

    // out[b][j][t] = silu( (sum_i w[j][i]*vp[i][t]) * sp[j][t] )
#pragma unroll
    for (int nb = 0; nb < NB; nb++) {
        const size_t obase = (size_t)(b0 + nb) * SS * VSA + 4 * tid;
#pragma unroll
        for (int j = 0; j < SS; j++) {
            float wj[SS];
#pragma unroll
            for (int i = 0; i < SS; i++) wj[i] = wbuf[nb][j * SS + i];  // LDS broadcast
            float att[4] = {0.f, 0.f, 0.f, 0.f};
#pragma unroll
            for (int i = 0; i < SS; i++) {
                const float wi = wj[i];
#pragma unroll
                for (int e = 0; e < 4; e++) att[e] += wi * vp[nb][i][e];
            }
            v4f o;
            o.x = silu_f(att[0] * sp4[j][0]);
            o.y = silu_f(att[1] * sp4[j][1]);
            o.z = silu_f(att[2] * sp4[j][2]);
            o.w = silu_f(att[3] * sp4[j][3]);
            __builtin_nontemporal_store(o, (v4f*)&out[obase + (size_t)j * VSA]);
        }
    }
}

extern "C" void kernel_launch(void* const* d_in, const int* in_sizes, int n_in,
                              void* d_out, int out_size, void* d_ws, size_t ws_size,
                              hipStream_t stream) {
    const float* values  = (const float*)d_in[0];
    const float* h       = (const float*)d_in[1];
    const float* symbols = (const float*)d_in[2];
    const float* gamma   = (const float*)d_in[3];
    const float* beta    = (const float*)d_in[4];
    float* out   = (float*)d_out;
    float* sp    = (float*)d_ws;                 // 5*1024 floats
    float* hpadG = (float*)d_ws + SS * VSA;      // 5*1092 floats (padded h)

    sp_kernel<<<SS, NT, 0, stream>>>(symbols, h, gamma, beta, sp, hpadG);
    main_kernel<<<BB / NB, NT, 0, stream>>>(values, hpadG, sp, gamma, beta, out);
}

// Round 3
// 244.399 us; speedup vs baseline: 3.0033x; 3.0033x over previous
//
#include <hip/hip_runtime.h>
#include <math.h>

#define BB   4096
#define SS   5
#define DD   64
#define HSZ  961
#define VSA  1024
#define NT   256
#define NB   2      // batches per block (NB=4 spills: live set > 128-reg cap)
#define LNE  1e-3f

// padded h layout: P[r] = h[r-POFF] for r in [POFF, POFF+960], else 0
#define POFF 64
#define PW   1092   // max index accessed = 1091; rows 16B-aligned

typedef float v4f __attribute__((ext_vector_type(4)));   // native vec for nontemporal

__device__ __forceinline__ float silu_f(float x) { return x / (1.f + __expf(-x)); }

// ---- DPP wave64 sum: pure-VALU reduction, no lgkmcnt traffic ----
// ctrl must be an immediate -> template parameter (clang checks pre-inline)
template <int CTRL>
__device__ __forceinline__ float dpp_add(float x) {
    int t = __builtin_amdgcn_update_dpp(0, __builtin_bit_cast(int, x),
                                        CTRL, 0xf, 0xf, false);
    return x + __builtin_bit_cast(float, t);
}
// full 64-lane sum; valid in lane 63
__device__ __forceinline__ float wave64_sum_l63(float x) {
    x = dpp_add<0x111>(x);  // row_shr:1
    x = dpp_add<0x112>(x);  // row_shr:2
    x = dpp_add<0x114>(x);  // row_shr:4
    x = dpp_add<0x118>(x);  // row_shr:8
    x = dpp_add<0x142>(x);  // row_bcast:15
    x = dpp_add<0x143>(x);  // row_bcast:31
    return x;
}

// ---- Kernel 1: sp = LN(silu(conv(symbols,h))); also emit zero-padded h ----
__global__ __launch_bounds__(NT)
void sp_kernel(const float* __restrict__ symbols, const float* __restrict__ h,
               const float* __restrict__ gamma, const float* __restrict__ beta,
               float* __restrict__ sp, float* __restrict__ hpadG)
{
    __shared__ float hpad[PW];
    __shared__ float red[4][2];
    const int s = blockIdx.x;
    const int tid = threadIdx.x;
    const int lane = tid & 63, wave = tid >> 6;

    for (int r = tid; r < PW; r += NT) {
        const float v = (r >= POFF && r <= POFF + 960) ? h[s * HSZ + (r - POFF)] : 0.f;
        hpad[r] = v;
        hpadG[s * PW + r] = v;        // padded copy for main_kernel
    }
    __syncthreads();

    const int base = 1020 - 4 * tid;
    float hw[8];
    *(float4*)&hw[0] = *(const float4*)&hpad[base];
    float acc[4] = {0.f, 0.f, 0.f, 0.f};
    const float* xp = symbols + s * DD;
#pragma unroll
    for (int c = 0; c < 16; c++) {
        *(float4*)&hw[4] = *(const float4*)&hpad[base + 4 * (c + 1)];
        const float x0 = xp[4 * c + 0];
        const float x1 = xp[4 * c + 1];
        const float x2 = xp[4 * c + 2];
        const float x3 = xp[4 * c + 3];
        acc[0] += x0 * hw[4]; acc[0] += x1 * hw[5]; acc[0] += x2 * hw[6]; acc[0] += x3 * hw[7];
        acc[1] += x0 * hw[3]; acc[1] += x1 * hw[4]; acc[1] += x2 * hw[5]; acc[1] += x3 * hw[6];
        acc[2] += x0 * hw[2]; acc[2] += x1 * hw[3]; acc[2] += x2 * hw[4]; acc[2] += x3 * hw[5];
        acc[3] += x0 * hw[1]; acc[3] += x1 * hw[2]; acc[3] += x2 * hw[3]; acc[3] += x3 * hw[4];
        hw[0] = hw[4]; hw[1] = hw[5]; hw[2] = hw[6]; hw[3] = hw[7];
    }

    float ys[4];
    float lsum = 0.f, lsq = 0.f;
#pragma unroll
    for (int j = 0; j < 4; j++) {
        ys[j] = silu_f(acc[j]);
        lsum += ys[j]; lsq += ys[j] * ys[j];
    }
    lsum = wave64_sum_l63(lsum);
    lsq  = wave64_sum_l63(lsq);
    if (lane == 63) { red[wave][0] = lsum; red[wave][1] = lsq; }
    __syncthreads();
    float s0 = 0.f, s1 = 0.f;
#pragma unroll
    for (int w = 0; w < 4; w++) { s0 += red[w][0]; s1 += red[w][1]; }
    const float mean = s0 * (1.f / VSA);
    const float rstd = rsqrtf(s1 * (1.f / VSA) - mean * mean + LNE);

    const float4 g4 = *(const float4*)&gamma[4 * tid];
    const float4 b4 = *(const float4*)&beta[4 * tid];
    float4 o;
    o.x = (ys[0] - mean) * rstd * g4.x + b4.x;
    o.y = (ys[1] - mean) * rstd * g4.y + b4.y;
    o.z = (ys[2] - mean) * rstd * g4.z + b4.z;
    o.w = (ys[3] - mean) * rstd * g4.w + b4.w;
    *(float4*)&sp[s * VSA + 4 * tid] = o;
}

// ------- Kernel 2: NB=2 batches per block --------------------------------
// values staged in LDS (uniform ds_read broadcast, in-order lgkm) instead of
// the s_load path (SMEM returns out-of-order -> full lgkmcnt(0) drains).
// __launch_bounds__(256,2): 128-VGPR cap fits the ~100-reg live set with
// NO spills; (256,4) forced a 64-reg allocation -> 2.4 GB of scratch HBM
// traffic (measured round 2: FETCH 809 MB, WRITE 1.64 GB, dur 3.5x worse).
__global__ __launch_bounds__(NT, 2)
void main_kernel(const float* __restrict__ values, const float* __restrict__ hpadG,
                 const float* __restrict__ sp, const float* __restrict__ gamma,
                 const float* __restrict__ beta, float* __restrict__ out)
{
    __shared__ __align__(16) float xs[NB][SS][DD];   // 2.5 KB block's values
    __shared__ float red[SS][NB][4][2];
    __shared__ int   scorered[NB][4][SS * SS];
    __shared__ float wbuf[NB][SS * SS];

    const int tid = threadIdx.x;
    const int lane = tid & 63, wave = tid >> 6;
    const int b0 = blockIdx.x * NB;
    const int base = 1020 - 4 * tid;

    // stage NB*5*64 = 640 contiguous floats, coalesced
    if (tid < (NB * SS * DD) / 4) {
        ((float4*)xs)[tid] =
            ((const float4*)(values + (size_t)b0 * (SS * DD)))[tid];
    }
    __syncthreads();

    float vp[NB][SS][4];   // conv->silu->LN results, t = 4*tid+j

    // conv + silu for all 5 s x NB batches; h window loaded once per (s,chunk)
#pragma unroll
    for (int s = 0; s < SS; s++) {
        const float* hp = hpadG + s * PW + base;
        float hw[8];
        *(float4*)&hw[0] = *(const float4*)hp;
        float acc[NB][4];
#pragma unroll
        for (int nb = 0; nb < NB; nb++)
            acc[nb][0] = acc[nb][1] = acc[nb][2] = acc[nb][3] = 0.f;
#pragma unroll
        for (int c = 0; c < 16; c++) {
            *(float4*)&hw[4] = *(const float4*)(hp + 4 * (c + 1));
#pragma unroll
            for (int nb = 0; nb < NB; nb++) {
                // uniform LDS broadcast read; in-order lgkm -> pipelines
                const float4 xv = *(const float4*)&xs[nb][s][4 * c];
                acc[nb][0] += xv.x * hw[4]; acc[nb][0] += xv.y * hw[5]; acc[nb][0] += xv.z * hw[6]; acc[nb][0] += xv.w * hw[7];
                acc[nb][1] += xv.x * hw[3]; acc[nb][1] += xv.y * hw[4]; acc[nb][1] += xv.z * hw[5]; acc[nb][1] += xv.w * hw[6];
                acc[nb][2] += xv.x * hw[2]; acc[nb][2] += xv.y * hw[3]; acc[nb][2] += xv.z * hw[4]; acc[nb][2] += xv.w * hw[5];
                acc[nb][3] += xv.x * hw[1]; acc[nb][3] += xv.y * hw[2]; acc[nb][3] += xv.z * hw[3]; acc[nb][3] += xv.w * hw[4];
            }
            hw[0] = hw[4]; hw[1] = hw[5]; hw[2] = hw[6]; hw[3] = hw[7];
        }
        // silu + LN partials per batch (pure-VALU DPP reduce)
#pragma unroll
        for (int nb = 0; nb < NB; nb++) {
            float lsum = 0.f, lsq = 0.f;
#pragma unroll
            for (int j = 0; j < 4; j++) {
                const float y = silu_f(acc[nb][j]);
                vp[nb][s][j] = y; lsum += y; lsq += y * y;
            }
            lsum = wave64_sum_l63(lsum);
            lsq  = wave64_sum_l63(lsq);
            if (lane == 63) { red[s][nb][wave][0] = lsum; red[s][nb][wave][1] = lsq; }
        }
    }
    __syncthreads();

    // LayerNorm epilogue in registers
    const float4 g4 = *(const float4*)&gamma[4 * tid];
    const float4 b4 = *(const float4*)&beta[4 * tid];
#pragma unroll
    for (int s = 0; s < SS; s++) {
#pragma unroll
        for (int nb = 0; nb < NB; nb++) {
            float s0 = 0.f, s1 = 0.f;
#pragma unroll
            for (int w = 0; w < 4; w++) { s0 += red[s][nb][w][0]; s1 += red[s][nb][w][1]; }
            const float mean = s0 * (1.f / VSA);
            const float rstd = rsqrtf(s1 * (1.f / VSA) - mean * mean + LNE);
            vp[nb][s][0] = (vp[nb][s][0] - mean) * rstd * g4.x + b4.x;
            vp[nb][s][1] = (vp[nb][s][1] - mean) * rstd * g4.y + b4.y;
            vp[nb][s][2] = (vp[nb][s][2] - mean) * rstd * g4.z + b4.z;
            vp[nb][s][3] = (vp[nb][s][3] - mean) * rstd * g4.w + b4.w;
        }
    }

    // sp fragments (batch-independent, L1/L2-hot)
    float sp4[SS][4];
#pragma unroll
    for (int i = 0; i < SS; i++)
        *(float4*)&sp4[i][0] = *(const float4*)&sp[i * VSA + 4 * tid];

    // scores via ballot: sign(a)*sign(b) = 1 - 2*[signbits differ]
#pragma unroll
    for (int nb = 0; nb < NB; nb++) {
        int neq[SS * SS];
#pragma unroll
        for (int p = 0; p < SS * SS; p++) neq[p] = 0;
#pragma unroll
        for (int jj = 0; jj < 4; jj++) {
            unsigned long long bvi[SS];
#pragma unroll
            for (int i = 0; i < SS; i++) bvi[i] = __ballot(vp[nb][i][jj] > 0.f);
#pragma unroll
            for (int j = 0; j < SS; j++) {
                const float sjv = sp4[j][jj];
#pragma unroll
                for (int i = 0; i < SS; i++) {
                    const unsigned long long bs = __ballot(vp[nb][i][jj] + sjv > 0.f);
                    neq[j * SS + i] += (int)__popcll(bvi[i] ^ bs);
                }
            }
        }
        if (lane == 0) {
#pragma unroll
            for (int p = 0; p < SS * SS; p++) scorered[nb][wave][p] = neq[p];
        }
    }
    __syncthreads();

    // softmax over i per (nb, j) — NB*SS threads
    if (tid < NB * SS) {
        const int nb = tid / SS, j = tid - nb * SS;
        float sc[SS];
#pragma unroll
        for (int i = 0; i < SS; i++) {
            const int nq = scorered[nb][0][j * SS + i] + scorered[nb][1][j * SS + i]
                         + scorered[nb][2][j * SS + i] + scorered[nb][3][j * SS + i];
            sc[i] = 1.f - (2.f / VSA) * (float)nq;
        }
        float m = sc[0];
#pragma unroll
        for (int i = 1; i < SS; i++) m = fmaxf(m, sc[i]);
        float e[SS], ssum = 0.f;
#pragma unroll
        for (int i = 0; i < SS; i++) { e[i] = __expf(sc[i] - m); ssum += e[i]; }
        const float inv = 1.f / ssum;
#pragma unroll
        for (int i = 0; i < SS; i++) wbuf[nb][j * SS + i] = e[i] * inv;
    }
    __syncthreads();

    // out[b][j][t] = silu( (sum_i w[j][i]*vp[i][t]) * sp[j][t] )
#pragma unroll
    for (int nb = 0; nb < NB; nb++) {
        const size_t obase = (size_t)(b0 + nb) * SS * VSA + 4 * tid;
#pragma unroll
        for (int j = 0; j < SS; j++) {
            float wj[SS];
#pragma unroll
            for (int i = 0; i < SS; i++) wj[i] = wbuf[nb][j * SS + i];  // LDS broadcast
            float att[4] = {0.f, 0.f, 0.f, 0.f};
#pragma unroll
            for (int i = 0; i < SS; i++) {
                const float wi = wj[i];
#pragma unroll
                for (int e = 0; e < 4; e++) att[e] += wi * vp[nb][i][e];
            }
            v4f o;
            o.x = silu_f(att[0] * sp4[j][0]);
            o.y = silu_f(att[1] * sp4[j][1]);
            o.z = silu_f(att[2] * sp4[j][2]);
            o.w = silu_f(att[3] * sp4[j][3]);
            __builtin_nontemporal_store(o, (v4f*)&out[obase + (size_t)j * VSA]);
        }
    }
}

extern "C" void kernel_launch(void* const* d_in, const int* in_sizes, int n_in,
                              void* d_out, int out_size, void* d_ws, size_t ws_size,
                              hipStream_t stream) {
    const float* values  = (const float*)d_in[0];
    const float* h       = (const float*)d_in[1];
    const float* symbols = (const float*)d_in[2];
    const float* gamma   = (const float*)d_in[3];
    const float* beta    = (const float*)d_in[4];
    float* out   = (float*)d_out;
    float* sp    = (float*)d_ws;                 // 5*1024 floats
    float* hpadG = (float*)d_ws + SS * VSA;      // 5*1092 floats (padded h)

    sp_kernel<<<SS, NT, 0, stream>>>(symbols, h, gamma, beta, sp, hpadG);
    main_kernel<<<BB / NB, NT, 0, stream>>>(values, hpadG, sp, gamma, beta, out);
}

// Round 4
// 240.534 us; speedup vs baseline: 3.0516x; 1.0161x over previous
//
#include <hip/hip_runtime.h>
#include <math.h>

#define BB   4096
#define SS   5
#define DD   64
#define HSZ  961
#define VSA  1024
#define NT   256
#define NB   2      // batches per block
#define LNE  1e-3f

// padded h layout: P[r] = h[r-POFF] for r in [POFF, POFF+960], else 0
#define POFF 64
#define PW   1092   // max index accessed = 1091; rows 16B-aligned (4368 B)

typedef float v4f __attribute__((ext_vector_type(4)));   // native vec for nontemporal

__device__ __forceinline__ float silu_f(float x) { return x / (1.f + __expf(-x)); }

// ---- DPP wave64 sum: pure-VALU reduction, no lgkmcnt traffic ----
template <int CTRL>
__device__ __forceinline__ float dpp_add(float x) {
    int t = __builtin_amdgcn_update_dpp(0, __builtin_bit_cast(int, x),
                                        CTRL, 0xf, 0xf, false);
    return x + __builtin_bit_cast(float, t);
}
// full 64-lane sum; valid in lane 63
__device__ __forceinline__ float wave64_sum_l63(float x) {
    x = dpp_add<0x111>(x);  // row_shr:1
    x = dpp_add<0x112>(x);  // row_shr:2
    x = dpp_add<0x114>(x);  // row_shr:4
    x = dpp_add<0x118>(x);  // row_shr:8
    x = dpp_add<0x142>(x);  // row_bcast:15
    x = dpp_add<0x143>(x);  // row_bcast:31
    return x;
}

// ---- Kernel 1: sp = LN(silu(conv(symbols,h))); also emit zero-padded h ----
__global__ __launch_bounds__(NT)
void sp_kernel(const float* __restrict__ symbols, const float* __restrict__ h,
               const float* __restrict__ gamma, const float* __restrict__ beta,
               float* __restrict__ sp, float* __restrict__ hpadG)
{
    __shared__ float hpad[PW];
    __shared__ float red[4][2];
    const int s = blockIdx.x;
    const int tid = threadIdx.x;
    const int lane = tid & 63, wave = tid >> 6;

    for (int r = tid; r < PW; r += NT) {
        const float v = (r >= POFF && r <= POFF + 960) ? h[s * HSZ + (r - POFF)] : 0.f;
        hpad[r] = v;
        hpadG[s * PW + r] = v;        // padded copy for main_kernel
    }
    __syncthreads();

    const int base = 1020 - 4 * tid;
    float hw[8];
    *(float4*)&hw[0] = *(const float4*)&hpad[base];
    float acc[4] = {0.f, 0.f, 0.f, 0.f};
    const float* xp = symbols + s * DD;
#pragma unroll
    for (int c = 0; c < 16; c++) {
        *(float4*)&hw[4] = *(const float4*)&hpad[base + 4 * (c + 1)];
        const float x0 = xp[4 * c + 0];
        const float x1 = xp[4 * c + 1];
        const float x2 = xp[4 * c + 2];
        const float x3 = xp[4 * c + 3];
        acc[0] += x0 * hw[4]; acc[0] += x1 * hw[5]; acc[0] += x2 * hw[6]; acc[0] += x3 * hw[7];
        acc[1] += x0 * hw[3]; acc[1] += x1 * hw[4]; acc[1] += x2 * hw[5]; acc[1] += x3 * hw[6];
        acc[2] += x0 * hw[2]; acc[2] += x1 * hw[3]; acc[2] += x2 * hw[4]; acc[2] += x3 * hw[5];
        acc[3] += x0 * hw[1]; acc[3] += x1 * hw[2]; acc[3] += x2 * hw[3]; acc[3] += x3 * hw[4];
        hw[0] = hw[4]; hw[1] = hw[5]; hw[2] = hw[6]; hw[3] = hw[7];
    }

    float ys[4];
    float lsum = 0.f, lsq = 0.f;
#pragma unroll
    for (int j = 0; j < 4; j++) {
        ys[j] = silu_f(acc[j]);
        lsum += ys[j]; lsq += ys[j] * ys[j];
    }
    lsum = wave64_sum_l63(lsum);
    lsq  = wave64_sum_l63(lsq);
    if (lane == 63) { red[wave][0] = lsum; red[wave][1] = lsq; }
    __syncthreads();
    float s0 = 0.f, s1 = 0.f;
#pragma unroll
    for (int w = 0; w < 4; w++) { s0 += red[w][0]; s1 += red[w][1]; }
    const float mean = s0 * (1.f / VSA);
    const float rstd = rsqrtf(s1 * (1.f / VSA) - mean * mean + LNE);

    const float4 g4 = *(const float4*)&gamma[4 * tid];
    const float4 b4 = *(const float4*)&beta[4 * tid];
    float4 o;
    o.x = (ys[0] - mean) * rstd * g4.x + b4.x;
    o.y = (ys[1] - mean) * rstd * g4.y + b4.y;
    o.z = (ys[2] - mean) * rstd * g4.z + b4.z;
    o.w = (ys[3] - mean) * rstd * g4.w + b4.w;
    *(float4*)&sp[s * VSA + 4 * tid] = o;
}

// ------- Kernel 2: NB=2 batches per block --------------------------------
// All conv operands staged in LDS:
//  - xs (values): uniform ds_read broadcast (in-order lgkm, no SMEM drains)
//  - hs (padded h, 21.8 KB): read from LDS instead of 80 pipelined global
//    float4 loads per thread.  Round 3 showed those vmcnt-pipelined loads
//    blew the 128-VGPR cap -> ~124 MB spill-store traffic (WRITE 207 MB vs
//    84 MB output).  With h in LDS the in-flight register demand collapses.
__global__ __launch_bounds__(NT, 2)
void main_kernel(const float* __restrict__ values, const float* __restrict__ hpadG,
                 const float* __restrict__ sp, const float* __restrict__ gamma,
                 const float* __restrict__ beta, float* __restrict__ out)
{
    __shared__ __align__(16) float hs[SS * PW];      // 21.8 KB padded h
    __shared__ __align__(16) float xs[NB][SS][DD];   // 2.5 KB block's values
    __shared__ float red[SS][NB][4][2];
    __shared__ int   scorered[NB][4][SS * SS];
    __shared__ float wbuf[NB][SS * SS];

    const int tid = threadIdx.x;
    const int lane = tid & 63, wave = tid >> 6;
    const int b0 = blockIdx.x * NB;
    const int base = 1020 - 4 * tid;

    // stage padded h: 5460 floats = 1365 float4, coalesced
    for (int i = tid; i < (SS * PW) / 4; i += NT)
        ((float4*)hs)[i] = ((const float4*)hpadG)[i];

    // stage NB*5*64 = 640 contiguous floats, coalesced
    if (tid < (NB * SS * DD) / 4) {
        ((float4*)xs)[tid] =
            ((const float4*)(values + (size_t)b0 * (SS * DD)))[tid];
    }
    __syncthreads();

    float vp[NB][SS][4];   // conv->silu->LN results, t = 4*tid+j

    // conv + silu for all 5 s x NB batches; everything from LDS
#pragma unroll
    for (int s = 0; s < SS; s++) {
        const float* hp = hs + s * PW + base;
        float hw[8];
        *(float4*)&hw[0] = *(const float4*)hp;
        float acc[NB][4];
#pragma unroll
        for (int nb = 0; nb < NB; nb++)
            acc[nb][0] = acc[nb][1] = acc[nb][2] = acc[nb][3] = 0.f;
#pragma unroll
        for (int c = 0; c < 16; c++) {
            *(float4*)&hw[4] = *(const float4*)(hp + 4 * (c + 1));
#pragma unroll
            for (int nb = 0; nb < NB; nb++) {
                // uniform LDS broadcast read
                const float4 xv = *(const float4*)&xs[nb][s][4 * c];
                acc[nb][0] += xv.x * hw[4]; acc[nb][0] += xv.y * hw[5]; acc[nb][0] += xv.z * hw[6]; acc[nb][0] += xv.w * hw[7];
                acc[nb][1] += xv.x * hw[3]; acc[nb][1] += xv.y * hw[4]; acc[nb][1] += xv.z * hw[5]; acc[nb][1] += xv.w * hw[6];
                acc[nb][2] += xv.x * hw[2]; acc[nb][2] += xv.y * hw[3]; acc[nb][2] += xv.z * hw[4]; acc[nb][2] += xv.w * hw[5];
                acc[nb][3] += xv.x * hw[1]; acc[nb][3] += xv.y * hw[2]; acc[nb][3] += xv.z * hw[3]; acc[nb][3] += xv.w * hw[4];
            }
            hw[0] = hw[4]; hw[1] = hw[5]; hw[2] = hw[6]; hw[3] = hw[7];
        }
        // silu + LN partials per batch (pure-VALU DPP reduce)
#pragma unroll
        for (int nb = 0; nb < NB; nb++) {
            float lsum = 0.f, lsq = 0.f;
#pragma unroll
            for (int j = 0; j < 4; j++) {
                const float y = silu_f(acc[nb][j]);
                vp[nb][s][j] = y; lsum += y; lsq += y * y;
            }
            lsum = wave64_sum_l63(lsum);
            lsq  = wave64_sum_l63(lsq);
            if (lane == 63) { red[s][nb][wave][0] = lsum; red[s][nb][wave][1] = lsq; }
        }
    }
    __syncthreads();

    // LayerNorm epilogue in registers
    const float4 g4 = *(const float4*)&gamma[4 * tid];
    const float4 b4 = *(const float4*)&beta[4 * tid];
#pragma unroll
    for (int s = 0; s < SS; s++) {
#pragma unroll
        for (int nb = 0; nb < NB; nb++) {
            float s0 = 0.f, s1 = 0.f;
#pragma unroll
            for (int w = 0; w < 4; w++) { s0 += red[s][nb][w][0]; s1 += red[s][nb][w][1]; }
            const float mean = s0 * (1.f / VSA);
            const float rstd = rsqrtf(s1 * (1.f / VSA) - mean * mean + LNE);
            vp[nb][s][0] = (vp[nb][s][0] - mean) * rstd * g4.x + b4.x;
            vp[nb][s][1] = (vp[nb][s][1] - mean) * rstd * g4.y + b4.y;
            vp[nb][s][2] = (vp[nb][s][2] - mean) * rstd * g4.z + b4.z;
            vp[nb][s][3] = (vp[nb][s][3] - mean) * rstd * g4.w + b4.w;
        }
    }

    // sp fragments (batch-independent, L1/L2-hot)
    float sp4[SS][4];
#pragma unroll
    for (int i = 0; i < SS; i++)
        *(float4*)&sp4[i][0] = *(const float4*)&sp[i * VSA + 4 * tid];

    // scores via ballot: sign(a)*sign(b) = 1 - 2*[signbits differ]
#pragma unroll
    for (int nb = 0; nb < NB; nb++) {
        int neq[SS * SS];
#pragma unroll
        for (int p = 0; p < SS * SS; p++) neq[p] = 0;
#pragma unroll
        for (int jj = 0; jj < 4; jj++) {
            unsigned long long bvi[SS];
#pragma unroll
            for (int i = 0; i < SS; i++) bvi[i] = __ballot(vp[nb][i][jj] > 0.f);
#pragma unroll
            for (int j = 0; j < SS; j++) {
                const float sjv = sp4[j][jj];
#pragma unroll
                for (int i = 0; i < SS; i++) {
                    const unsigned long long bs = __ballot(vp[nb][i][jj] + sjv > 0.f);
                    neq[j * SS + i] += (int)__popcll(bvi[i] ^ bs);
                }
            }
        }
        if (lane == 0) {
#pragma unroll
            for (int p = 0; p < SS * SS; p++) scorered[nb][wave][p] = neq[p];
        }
    }
    __syncthreads();

    // softmax over i per (nb, j) — NB*SS threads
    if (tid < NB * SS) {
        const int nb = tid / SS, j = tid - nb * SS;
        float sc[SS];
#pragma unroll
        for (int i = 0; i < SS; i++) {
            const int nq = scorered[nb][0][j * SS + i] + scorered[nb][1][j * SS + i]
                         + scorered[nb][2][j * SS + i] + scorered[nb][3][j * SS + i];
            sc[i] = 1.f - (2.f / VSA) * (float)nq;
        }
        float m = sc[0];
#pragma unroll
        for (int i = 1; i < SS; i++) m = fmaxf(m, sc[i]);
        float e[SS], ssum = 0.f;
#pragma unroll
        for (int i = 0; i < SS; i++) { e[i] = __expf(sc[i] - m); ssum += e[i]; }
        const float inv = 1.f / ssum;
#pragma unroll
        for (int i = 0; i < SS; i++) wbuf[nb][j * SS + i] = e[i] * inv;
    }
    __syncthreads();

    // out[b][j][t] = silu( (sum_i w[j][i]*vp[i][t]) * sp[j][t] )
#pragma unroll
    for (int nb = 0; nb < NB; nb++) {
        const size_t obase = (size_t)(b0 + nb) * SS * VSA + 4 * tid;
#pragma unroll
        for (int j = 0; j < SS; j++) {
            float wj[SS];
#pragma unroll
            for (int i = 0; i < SS; i++) wj[i] = wbuf[nb][j * SS + i];  // LDS broadcast
            float att[4] = {0.f, 0.f, 0.f, 0.f};
#pragma unroll
            for (int i = 0; i < SS; i++) {
                const float wi = wj[i];
#pragma unroll
                for (int e = 0; e < 4; e++) att[e] += wi * vp[nb][i][e];
            }
            v4f o;
            o.x = silu_f(att[0] * sp4[j][0]);
            o.y = silu_f(att[1] * sp4[j][1]);
            o.z = silu_f(att[2] * sp4[j][2]);
            o.w = silu_f(att[3] * sp4[j][3]);
            __builtin_nontemporal_store(o, (v4f*)&out[obase + (size_t)j * VSA]);
        }
    }
}

extern "C" void kernel_launch(void* const* d_in, const int* in_sizes, int n_in,
                              void* d_out, int out_size, void* d_ws, size_t ws_size,
                              hipStream_t stream) {
    const float* values  = (const float*)d_in[0];
    const float* h       = (const float*)d_in[1];
    const float* symbols = (const float*)d_in[2];
    const float* gamma   = (const float*)d_in[3];
    const float* beta    = (const float*)d_in[4];
    float* out   = (float*)d_out;
    float* sp    = (float*)d_ws;                 // 5*1024 floats
    float* hpadG = (float*)d_ws + SS * VSA;      // 5*1092 floats (padded h)

    sp_kernel<<<SS, NT, 0, stream>>>(symbols, h, gamma, beta, sp, hpadG);
    main_kernel<<<BB / NB, NT, 0, stream>>>(values, hpadG, sp, gamma, beta, out);
}

// Round 5
// 187.936 us; speedup vs baseline: 3.9057x; 1.2799x over previous
//
#include <hip/hip_runtime.h>
#include <math.h>

#define BB   4096
#define SS   5
#define DD   64
#define HSZ  961
#define VSA  1024
#define NT   256
#define NB   2      // batches per block
#define LNE  1e-3f

// padded h layout: P[r] = h[r-POFF] for r in [POFF, POFF+960], else 0
#define POFF 64
#define PW   1092   // max index accessed = 1091; rows 16B-aligned (4368 B)

typedef float v4f __attribute__((ext_vector_type(4)));   // native vec for nontemporal

__device__ __forceinline__ float silu_f(float x) { return x / (1.f + __expf(-x)); }

// ---- DPP wave64 sum: pure-VALU reduction, no lgkmcnt traffic ----
template <int CTRL>
__device__ __forceinline__ float dpp_add(float x) {
    int t = __builtin_amdgcn_update_dpp(0, __builtin_bit_cast(int, x),
                                        CTRL, 0xf, 0xf, false);
    return x + __builtin_bit_cast(float, t);
}
// full 64-lane sum; valid in lane 63
__device__ __forceinline__ float wave64_sum_l63(float x) {
    x = dpp_add<0x111>(x);  // row_shr:1
    x = dpp_add<0x112>(x);  // row_shr:2
    x = dpp_add<0x114>(x);  // row_shr:4
    x = dpp_add<0x118>(x);  // row_shr:8
    x = dpp_add<0x142>(x);  // row_bcast:15
    x = dpp_add<0x143>(x);  // row_bcast:31
    return x;
}

// ---- Kernel 1: sp = LN(silu(conv(symbols,h))); also emit zero-padded h ----
__global__ __launch_bounds__(NT)
void sp_kernel(const float* __restrict__ symbols, const float* __restrict__ h,
               const float* __restrict__ gamma, const float* __restrict__ beta,
               float* __restrict__ sp, float* __restrict__ hpadG)
{
    __shared__ float hpad[PW];
    __shared__ float red[4][2];
    const int s = blockIdx.x;
    const int tid = threadIdx.x;
    const int lane = tid & 63, wave = tid >> 6;

    for (int r = tid; r < PW; r += NT) {
        const float v = (r >= POFF && r <= POFF + 960) ? h[s * HSZ + (r - POFF)] : 0.f;
        hpad[r] = v;
        hpadG[s * PW + r] = v;        // padded copy for main_kernel
    }
    __syncthreads();

    const int base = 1020 - 4 * tid;
    float hw[8];
    *(float4*)&hw[0] = *(const float4*)&hpad[base];
    float acc[4] = {0.f, 0.f, 0.f, 0.f};
    const float* xp = symbols + s * DD;
#pragma unroll
    for (int c = 0; c < 16; c++) {
        *(float4*)&hw[4] = *(const float4*)&hpad[base + 4 * (c + 1)];
        const float x0 = xp[4 * c + 0];
        const float x1 = xp[4 * c + 1];
        const float x2 = xp[4 * c + 2];
        const float x3 = xp[4 * c + 3];
        acc[0] += x0 * hw[4]; acc[0] += x1 * hw[5]; acc[0] += x2 * hw[6]; acc[0] += x3 * hw[7];
        acc[1] += x0 * hw[3]; acc[1] += x1 * hw[4]; acc[1] += x2 * hw[5]; acc[1] += x3 * hw[6];
        acc[2] += x0 * hw[2]; acc[2] += x1 * hw[3]; acc[2] += x2 * hw[4]; acc[2] += x3 * hw[5];
        acc[3] += x0 * hw[1]; acc[3] += x1 * hw[2]; acc[3] += x2 * hw[3]; acc[3] += x3 * hw[4];
        hw[0] = hw[4]; hw[1] = hw[5]; hw[2] = hw[6]; hw[3] = hw[7];
    }

    float ys[4];
    float lsum = 0.f, lsq = 0.f;
#pragma unroll
    for (int j = 0; j < 4; j++) {
        ys[j] = silu_f(acc[j]);
        lsum += ys[j]; lsq += ys[j] * ys[j];
    }
    lsum = wave64_sum_l63(lsum);
    lsq  = wave64_sum_l63(lsq);
    if (lane == 63) { red[wave][0] = lsum; red[wave][1] = lsq; }
    __syncthreads();
    float s0 = 0.f, s1 = 0.f;
#pragma unroll
    for (int w = 0; w < 4; w++) { s0 += red[w][0]; s1 += red[w][1]; }
    const float mean = s0 * (1.f / VSA);
    const float rstd = rsqrtf(s1 * (1.f / VSA) - mean * mean + LNE);

    const float4 g4 = *(const float4*)&gamma[4 * tid];
    const float4 b4 = *(const float4*)&beta[4 * tid];
    float4 o;
    o.x = (ys[0] - mean) * rstd * g4.x + b4.x;
    o.y = (ys[1] - mean) * rstd * g4.y + b4.y;
    o.z = (ys[2] - mean) * rstd * g4.z + b4.z;
    o.w = (ys[3] - mean) * rstd * g4.w + b4.w;
    *(float4*)&sp[s * VSA + 4 * tid] = o;
}

// ------- Kernel 2: NB=2 batches per block --------------------------------
// R4 post-mortem: spill (~120 MB scratch writes) persisted with h in LDS ->
// cause is the SCHEDULER, not any one load path: with the 5x16 conv fully
// unrolled and the DPP reduce being pure VALU (no lgkm ops), LLVM hoists the
// next s-body's ~49 independent ds_read_b128 (~196 VGPRs of destinations)
// into the reduce chain; allocator spills at the 128 cap.
// Fix: real c-loop (#pragma unroll 1 -> <=3 ds_reads in flight) +
// sched_barrier(0) fences around each s-body's reduce so loads can't be
// hoisted across. All vp/acc indices remain compile-time constants.
__global__ __launch_bounds__(NT, 2)
void main_kernel(const float* __restrict__ values, const float* __restrict__ hpadG,
                 const float* __restrict__ sp, const float* __restrict__ gamma,
                 const float* __restrict__ beta, float* __restrict__ out)
{
    __shared__ __align__(16) float hs[SS * PW];      // 21.8 KB padded h
    __shared__ __align__(16) float xs[NB][SS][DD];   // 2.5 KB block's values
    __shared__ float red[SS][NB][4][2];
    __shared__ int   scorered[NB][4][SS * SS];
    __shared__ float wbuf[NB][SS * SS];

    const int tid = threadIdx.x;
    const int lane = tid & 63, wave = tid >> 6;
    const int b0 = blockIdx.x * NB;
    const int base = 1020 - 4 * tid;

    // stage padded h: 5460 floats = 1365 float4, coalesced
    for (int i = tid; i < (SS * PW) / 4; i += NT)
        ((float4*)hs)[i] = ((const float4*)hpadG)[i];

    // stage NB*5*64 = 640 contiguous floats, coalesced
    if (tid < (NB * SS * DD) / 4) {
        ((float4*)xs)[tid] =
            ((const float4*)(values + (size_t)b0 * (SS * DD)))[tid];
    }
    __syncthreads();

    float vp[NB][SS][4];   // conv->silu->LN results, t = 4*tid+j

    // conv + silu for all 5 s x NB batches; everything from LDS
#pragma unroll
    for (int s = 0; s < SS; s++) {
        const float* hp = hs + s * PW + base;
        float hw[8];
        *(float4*)&hw[0] = *(const float4*)hp;
        float acc[NB][4];
#pragma unroll
        for (int nb = 0; nb < NB; nb++)
            acc[nb][0] = acc[nb][1] = acc[nb][2] = acc[nb][3] = 0.f;
        // REAL loop: bounds in-flight ds_reads to ~1 iteration (3 b128)
#pragma unroll 1
        for (int c = 0; c < 16; c++) {
            *(float4*)&hw[4] = *(const float4*)(hp + 4 * c + 4);
#pragma unroll
            for (int nb = 0; nb < NB; nb++) {
                // uniform LDS broadcast read
                const float4 xv = *(const float4*)&xs[nb][s][4 * c];
                acc[nb][0] += xv.x * hw[4]; acc[nb][0] += xv.y * hw[5]; acc[nb][0] += xv.z * hw[6]; acc[nb][0] += xv.w * hw[7];
                acc[nb][1] += xv.x * hw[3]; acc[nb][1] += xv.y * hw[4]; acc[nb][1] += xv.z * hw[5]; acc[nb][1] += xv.w * hw[6];
                acc[nb][2] += xv.x * hw[2]; acc[nb][2] += xv.y * hw[3]; acc[nb][2] += xv.z * hw[4]; acc[nb][2] += xv.w * hw[5];
                acc[nb][3] += xv.x * hw[1]; acc[nb][3] += xv.y * hw[2]; acc[nb][3] += xv.z * hw[3]; acc[nb][3] += xv.w * hw[4];
            }
            hw[0] = hw[4]; hw[1] = hw[5]; hw[2] = hw[6]; hw[3] = hw[7];
        }
        // fence: nothing from the reduce below moves up into the c-loop,
        // nothing from the NEXT s-body (its ds_reads) moves into the reduce
        __builtin_amdgcn_sched_barrier(0);
        // silu + LN partials per batch (pure-VALU DPP reduce)
#pragma unroll
        for (int nb = 0; nb < NB; nb++) {
            float lsum = 0.f, lsq = 0.f;
#pragma unroll
            for (int j = 0; j < 4; j++) {
                const float y = silu_f(acc[nb][j]);
                vp[nb][s][j] = y; lsum += y; lsq += y * y;
            }
            lsum = wave64_sum_l63(lsum);
            lsq  = wave64_sum_l63(lsq);
            if (lane == 63) { red[s][nb][wave][0] = lsum; red[s][nb][wave][1] = lsq; }
        }
        __builtin_amdgcn_sched_barrier(0);
    }
    __syncthreads();

    // LayerNorm epilogue in registers
    const float4 g4 = *(const float4*)&gamma[4 * tid];
    const float4 b4 = *(const float4*)&beta[4 * tid];
#pragma unroll
    for (int s = 0; s < SS; s++) {
#pragma unroll
        for (int nb = 0; nb < NB; nb++) {
            float s0 = 0.f, s1 = 0.f;
#pragma unroll
            for (int w = 0; w < 4; w++) { s0 += red[s][nb][w][0]; s1 += red[s][nb][w][1]; }
            const float mean = s0 * (1.f / VSA);
            const float rstd = rsqrtf(s1 * (1.f / VSA) - mean * mean + LNE);
            vp[nb][s][0] = (vp[nb][s][0] - mean) * rstd * g4.x + b4.x;
            vp[nb][s][1] = (vp[nb][s][1] - mean) * rstd * g4.y + b4.y;
            vp[nb][s][2] = (vp[nb][s][2] - mean) * rstd * g4.z + b4.z;
            vp[nb][s][3] = (vp[nb][s][3] - mean) * rstd * g4.w + b4.w;
        }
    }

    // sp fragments (batch-independent, L1/L2-hot)
    float sp4[SS][4];
#pragma unroll
    for (int i = 0; i < SS; i++)
        *(float4*)&sp4[i][0] = *(const float4*)&sp[i * VSA + 4 * tid];

    // scores via ballot: sign(a)*sign(b) = 1 - 2*[signbits differ]
#pragma unroll
    for (int nb = 0; nb < NB; nb++) {
        int neq[SS * SS];
#pragma unroll
        for (int p = 0; p < SS * SS; p++) neq[p] = 0;
#pragma unroll
        for (int jj = 0; jj < 4; jj++) {
            unsigned long long bvi[SS];
#pragma unroll
            for (int i = 0; i < SS; i++) bvi[i] = __ballot(vp[nb][i][jj] > 0.f);
#pragma unroll
            for (int j = 0; j < SS; j++) {
                const float sjv = sp4[j][jj];
#pragma unroll
                for (int i = 0; i < SS; i++) {
                    const unsigned long long bs = __ballot(vp[nb][i][jj] + sjv > 0.f);
                    neq[j * SS + i] += (int)__popcll(bvi[i] ^ bs);
                }
            }
        }
        if (lane == 0) {
#pragma unroll
            for (int p = 0; p < SS * SS; p++) scorered[nb][wave][p] = neq[p];
        }
    }
    __syncthreads();

    // softmax over i per (nb, j) — NB*SS threads
    if (tid < NB * SS) {
        const int nb = tid / SS, j = tid - nb * SS;
        float sc[SS];
#pragma unroll
        for (int i = 0; i < SS; i++) {
            const int nq = scorered[nb][0][j * SS + i] + scorered[nb][1][j * SS + i]
                         + scorered[nb][2][j * SS + i] + scorered[nb][3][j * SS + i];
            sc[i] = 1.f - (2.f / VSA) * (float)nq;
        }
        float m = sc[0];
#pragma unroll
        for (int i = 1; i < SS; i++) m = fmaxf(m, sc[i]);
        float e[SS], ssum = 0.f;
#pragma unroll
        for (int i = 0; i < SS; i++) { e[i] = __expf(sc[i] - m); ssum += e[i]; }
        const float inv = 1.f / ssum;
#pragma unroll
        for (int i = 0; i < SS; i++) wbuf[nb][j * SS + i] = e[i] * inv;
    }
    __syncthreads();

    // out[b][j][t] = silu( (sum_i w[j][i]*vp[i][t]) * sp[j][t] )
#pragma unroll
    for (int nb = 0; nb < NB; nb++) {
        const size_t obase = (size_t)(b0 + nb) * SS * VSA + 4 * tid;
#pragma unroll
        for (int j = 0; j < SS; j++) {
            float wj[SS];
#pragma unroll
            for (int i = 0; i < SS; i++) wj[i] = wbuf[nb][j * SS + i];  // LDS broadcast
            float att[4] = {0.f, 0.f, 0.f, 0.f};
#pragma unroll
            for (int i = 0; i < SS; i++) {
                const float wi = wj[i];
#pragma unroll
                for (int e = 0; e < 4; e++) att[e] += wi * vp[nb][i][e];
            }
            v4f o;
            o.x = silu_f(att[0] * sp4[j][0]);
            o.y = silu_f(att[1] * sp4[j][1]);
            o.z = silu_f(att[2] * sp4[j][2]);
            o.w = silu_f(att[3] * sp4[j][3]);
            __builtin_nontemporal_store(o, (v4f*)&out[obase + (size_t)j * VSA]);
        }
    }
}

extern "C" void kernel_launch(void* const* d_in, const int* in_sizes, int n_in,
                              void* d_out, int out_size, void* d_ws, size_t ws_size,
                              hipStream_t stream) {
    const float* values  = (const float*)d_in[0];
    const float* h       = (const float*)d_in[1];
    const float* symbols = (const float*)d_in[2];
    const float* gamma   = (const float*)d_in[3];
    const float* beta    = (const float*)d_in[4];
    float* out   = (float*)d_out;
    float* sp    = (float*)d_ws;                 // 5*1024 floats
    float* hpadG = (float*)d_ws + SS * VSA;      // 5*1092 floats (padded h)

    sp_kernel<<<SS, NT, 0, stream>>>(symbols, h, gamma, beta, sp, hpadG);
    main_kernel<<<BB / NB, NT, 0, stream>>>(values, hpadG, sp, gamma, beta, out);
}

// Round 6
// 169.715 us; speedup vs baseline: 4.3250x; 1.1074x over previous
//
#include <hip/hip_runtime.h>
#include <math.h>

#define BB   4096
#define SS   5
#define DD   64
#define HSZ  961
#define VSA  1024
#define NT   256
#define NB   2      // batches per block (packed pairwise into v_pk_fma_f32)
#define LNE  1e-3f

// padded h layout: P[r] = h[r-POFF] for r in [POFF, POFF+960], else 0
#define POFF 64
#define PW   1092   // max index accessed = 1091 (incl. +1-iter prefetch); 16B rows

typedef float v4f __attribute__((ext_vector_type(4)));   // native vec for nontemporal
typedef float v2f __attribute__((ext_vector_type(2)));   // packed-fp32 pair (nb0,nb1)

__device__ __forceinline__ float silu_f(float x) { return x / (1.f + __expf(-x)); }
__device__ __forceinline__ v2f splat2(float x) { v2f r; r.x = x; r.y = x; return r; }

// ---- DPP wave64 sum: pure-VALU reduction, no lgkmcnt traffic ----
template <int CTRL>
__device__ __forceinline__ float dpp_add(float x) {
    int t = __builtin_amdgcn_update_dpp(0, __builtin_bit_cast(int, x),
                                        CTRL, 0xf, 0xf, false);
    return x + __builtin_bit_cast(float, t);
}
// full 64-lane sum; valid in lane 63
__device__ __forceinline__ float wave64_sum_l63(float x) {
    x = dpp_add<0x111>(x);  // row_shr:1
    x = dpp_add<0x112>(x);  // row_shr:2
    x = dpp_add<0x114>(x);  // row_shr:4
    x = dpp_add<0x118>(x);  // row_shr:8
    x = dpp_add<0x142>(x);  // row_bcast:15
    x = dpp_add<0x143>(x);  // row_bcast:31
    return x;
}

// ---- Kernel 1: sp = LN(silu(conv(symbols,h))); also emit zero-padded h ----
__global__ __launch_bounds__(NT)
void sp_kernel(const float* __restrict__ symbols, const float* __restrict__ h,
               const float* __restrict__ gamma, const float* __restrict__ beta,
               float* __restrict__ sp, float* __restrict__ hpadG)
{
    __shared__ float hpad[PW];
    __shared__ float red[4][2];
    const int s = blockIdx.x;
    const int tid = threadIdx.x;
    const int lane = tid & 63, wave = tid >> 6;

    for (int r = tid; r < PW; r += NT) {
        const float v = (r >= POFF && r <= POFF + 960) ? h[s * HSZ + (r - POFF)] : 0.f;
        hpad[r] = v;
        hpadG[s * PW + r] = v;        // padded copy for main_kernel
    }
    __syncthreads();

    const int base = 1020 - 4 * tid;
    float hw[8];
    *(float4*)&hw[0] = *(const float4*)&hpad[base];
    float acc[4] = {0.f, 0.f, 0.f, 0.f};
    const float* xp = symbols + s * DD;
#pragma unroll
    for (int c = 0; c < 16; c++) {
        *(float4*)&hw[4] = *(const float4*)&hpad[base + 4 * (c + 1)];
        const float x0 = xp[4 * c + 0];
        const float x1 = xp[4 * c + 1];
        const float x2 = xp[4 * c + 2];
        const float x3 = xp[4 * c + 3];
        acc[0] += x0 * hw[4]; acc[0] += x1 * hw[5]; acc[0] += x2 * hw[6]; acc[0] += x3 * hw[7];
        acc[1] += x0 * hw[3]; acc[1] += x1 * hw[4]; acc[1] += x2 * hw[5]; acc[1] += x3 * hw[6];
        acc[2] += x0 * hw[2]; acc[2] += x1 * hw[3]; acc[2] += x2 * hw[4]; acc[2] += x3 * hw[5];
        acc[3] += x0 * hw[1]; acc[3] += x1 * hw[2]; acc[3] += x2 * hw[3]; acc[3] += x3 * hw[4];
        hw[0] = hw[4]; hw[1] = hw[5]; hw[2] = hw[6]; hw[3] = hw[7];
    }

    float ys[4];
    float lsum = 0.f, lsq = 0.f;
#pragma unroll
    for (int j = 0; j < 4; j++) {
        ys[j] = silu_f(acc[j]);
        lsum += ys[j]; lsq += ys[j] * ys[j];
    }
    lsum = wave64_sum_l63(lsum);
    lsq  = wave64_sum_l63(lsq);
    if (lane == 63) { red[wave][0] = lsum; red[wave][1] = lsq; }
    __syncthreads();
    float s0 = 0.f, s1 = 0.f;
#pragma unroll
    for (int w = 0; w < 4; w++) { s0 += red[w][0]; s1 += red[w][1]; }
    const float mean = s0 * (1.f / VSA);
    const float rstd = rsqrtf(s1 * (1.f / VSA) - mean * mean + LNE);

    const float4 g4 = *(const float4*)&gamma[4 * tid];
    const float4 b4 = *(const float4*)&beta[4 * tid];
    float4 o;
    o.x = (ys[0] - mean) * rstd * g4.x + b4.x;
    o.y = (ys[1] - mean) * rstd * g4.y + b4.y;
    o.z = (ys[2] - mean) * rstd * g4.z + b4.z;
    o.w = (ys[3] - mean) * rstd * g4.w + b4.w;
    *(float4*)&sp[s * VSA + 4 * tid] = o;
}

// ------- Kernel 2: NB=2 batches per block --------------------------------
// R5 confirmed: spill was scheduler-induced; per-region sched_barrier(0)
// fences bound the live set (WRITE dropped to exactly the 84 MB output).
// R6: (a) software-pipeline the conv at prefetch distance 1 under FULL
// unroll (fence per c-step keeps in-flight to ~1 iter; unroll renames away
// the 4-mov window shift); (b) pack the two batches into v_pk_fma_f32 via
// an interleaved xsI[s][d][nb] LDS layout (uniform ds_read_b64 broadcast
// yields the (nb0,nb1) pair). FMA order per accumulator unchanged ->
// bit-identical results.
__global__ __launch_bounds__(NT, 2)
void main_kernel(const float* __restrict__ values, const float* __restrict__ hpadG,
                 const float* __restrict__ sp, const float* __restrict__ gamma,
                 const float* __restrict__ beta, float* __restrict__ out)
{
    __shared__ __align__(16) float hs[SS * PW];       // 21.8 KB padded h
    __shared__ __align__(16) float xsI[SS][DD][NB];   // 2.5 KB values, nb-interleaved
    __shared__ float red[SS][NB][4][2];
    __shared__ int   scorered[NB][4][SS * SS];
    __shared__ float wbuf[NB][SS * SS];

    const int tid = threadIdx.x;
    const int lane = tid & 63, wave = tid >> 6;
    const int b0 = blockIdx.x * NB;
    const int base = 1020 - 4 * tid;

    // stage padded h: 5460 floats = 1365 float4, coalesced
    for (int i = tid; i < (SS * PW) / 4; i += NT)
        ((float4*)hs)[i] = ((const float4*)hpadG)[i];

    // stage values nb-interleaved: xsI[s][d] = {v[b0][s][d], v[b0+1][s][d]}
    for (int i = tid; i < SS * DD; i += NT) {
        v2f v;
        v.x = values[(size_t)(b0 + 0) * (SS * DD) + i];
        v.y = values[(size_t)(b0 + 1) * (SS * DD) + i];
        ((v2f*)xsI)[i] = v;
    }
    __syncthreads();

    float vp[NB][SS][4];   // conv->silu->LN results, t = 4*tid+j

    // conv + silu for all 5 s; both batches packed per v_pk_fma_f32
#pragma unroll
    for (int s = 0; s < SS; s++) {
        const float* hp = hs + s * PW + base;
        const v2f* xp = (const v2f*)&xsI[s][0][0];
        // preload c=0 operands
        float4 hLo = *(const float4*)hp;         // taps 4c+0..3
        float4 hHi = *(const float4*)(hp + 4);   // taps 4c+4..7
        v2f x0 = xp[0], x1 = xp[1], x2 = xp[2], x3 = xp[3];
        v2f acc2[4] = {};
#pragma unroll
        for (int c = 0; c < 16; c++) {
            // prefetch c+1 operands (region c = {loads c+1, FMAs c})
            float4 hNx = {};
            v2f n0 = {}, n1 = {}, n2 = {}, n3 = {};
            if (c < 15) {
                hNx = *(const float4*)(hp + 4 * c + 8);   // max idx 1091 < PW
                n0 = xp[4 * c + 4]; n1 = xp[4 * c + 5];
                n2 = xp[4 * c + 6]; n3 = xp[4 * c + 7];
            }
            // old hw mapping: hw[0..3]=hLo, hw[4..7]=hHi (same FMA order)
            acc2[0] = __builtin_elementwise_fma(x0, splat2(hHi.x), acc2[0]);
            acc2[0] = __builtin_elementwise_fma(x1, splat2(hHi.y), acc2[0]);
            acc2[0] = __builtin_elementwise_fma(x2, splat2(hHi.z), acc2[0]);
            acc2[0] = __builtin_elementwise_fma(x3, splat2(hHi.w), acc2[0]);
            acc2[1] = __builtin_elementwise_fma(x0, splat2(hLo.w), acc2[1]);
            acc2[1] = __builtin_elementwise_fma(x1, splat2(hHi.x), acc2[1]);
            acc2[1] = __builtin_elementwise_fma(x2, splat2(hHi.y), acc2[1]);
            acc2[1] = __builtin_elementwise_fma(x3, splat2(hHi.z), acc2[1]);
            acc2[2] = __builtin_elementwise_fma(x0, splat2(hLo.z), acc2[2]);
            acc2[2] = __builtin_elementwise_fma(x1, splat2(hLo.w), acc2[2]);
            acc2[2] = __builtin_elementwise_fma(x2, splat2(hHi.x), acc2[2]);
            acc2[2] = __builtin_elementwise_fma(x3, splat2(hHi.y), acc2[2]);
            acc2[3] = __builtin_elementwise_fma(x0, splat2(hLo.y), acc2[3]);
            acc2[3] = __builtin_elementwise_fma(x1, splat2(hLo.z), acc2[3]);
            acc2[3] = __builtin_elementwise_fma(x2, splat2(hLo.w), acc2[3]);
            acc2[3] = __builtin_elementwise_fma(x3, splat2(hHi.x), acc2[3]);
            // fence: bounds scheduler lookahead to one iteration of loads
            __builtin_amdgcn_sched_barrier(0);
            hLo = hHi; hHi = hNx;              // renamed away under full unroll
            x0 = n0; x1 = n1; x2 = n2; x3 = n3;
        }
        __builtin_amdgcn_sched_barrier(0);
        // silu + LN partials per batch (pure-VALU DPP reduce)
#pragma unroll
        for (int nb = 0; nb < NB; nb++) {
            float lsum = 0.f, lsq = 0.f;
#pragma unroll
            for (int j = 0; j < 4; j++) {
                const float y = silu_f(acc2[j][nb]);
                vp[nb][s][j] = y; lsum += y; lsq += y * y;
            }
            lsum = wave64_sum_l63(lsum);
            lsq  = wave64_sum_l63(lsq);
            if (lane == 63) { red[s][nb][wave][0] = lsum; red[s][nb][wave][1] = lsq; }
        }
        __builtin_amdgcn_sched_barrier(0);
    }
    __syncthreads();

    // LayerNorm epilogue in registers
    const float4 g4 = *(const float4*)&gamma[4 * tid];
    const float4 b4 = *(const float4*)&beta[4 * tid];
#pragma unroll
    for (int s = 0; s < SS; s++) {
#pragma unroll
        for (int nb = 0; nb < NB; nb++) {
            float s0 = 0.f, s1 = 0.f;
#pragma unroll
            for (int w = 0; w < 4; w++) { s0 += red[s][nb][w][0]; s1 += red[s][nb][w][1]; }
            const float mean = s0 * (1.f / VSA);
            const float rstd = rsqrtf(s1 * (1.f / VSA) - mean * mean + LNE);
            vp[nb][s][0] = (vp[nb][s][0] - mean) * rstd * g4.x + b4.x;
            vp[nb][s][1] = (vp[nb][s][1] - mean) * rstd * g4.y + b4.y;
            vp[nb][s][2] = (vp[nb][s][2] - mean) * rstd * g4.z + b4.z;
            vp[nb][s][3] = (vp[nb][s][3] - mean) * rstd * g4.w + b4.w;
        }
    }

    // sp fragments (batch-independent, L1/L2-hot)
    float sp4[SS][4];
#pragma unroll
    for (int i = 0; i < SS; i++)
        *(float4*)&sp4[i][0] = *(const float4*)&sp[i * VSA + 4 * tid];

    // scores via ballot: sign(a)*sign(b) = 1 - 2*[signbits differ]
#pragma unroll
    for (int nb = 0; nb < NB; nb++) {
        int neq[SS * SS];
#pragma unroll
        for (int p = 0; p < SS * SS; p++) neq[p] = 0;
#pragma unroll
        for (int jj = 0; jj < 4; jj++) {
            unsigned long long bvi[SS];
#pragma unroll
            for (int i = 0; i < SS; i++) bvi[i] = __ballot(vp[nb][i][jj] > 0.f);
#pragma unroll
            for (int j = 0; j < SS; j++) {
                const float sjv = sp4[j][jj];
#pragma unroll
                for (int i = 0; i < SS; i++) {
                    const unsigned long long bs = __ballot(vp[nb][i][jj] + sjv > 0.f);
                    neq[j * SS + i] += (int)__popcll(bvi[i] ^ bs);
                }
            }
        }
        if (lane == 0) {
#pragma unroll
            for (int p = 0; p < SS * SS; p++) scorered[nb][wave][p] = neq[p];
        }
    }
    __syncthreads();

    // softmax over i per (nb, j) — NB*SS threads
    if (tid < NB * SS) {
        const int nb = tid / SS, j = tid - nb * SS;
        float sc[SS];
#pragma unroll
        for (int i = 0; i < SS; i++) {
            const int nq = scorered[nb][0][j * SS + i] + scorered[nb][1][j * SS + i]
                         + scorered[nb][2][j * SS + i] + scorered[nb][3][j * SS + i];
            sc[i] = 1.f - (2.f / VSA) * (float)nq;
        }
        float m = sc[0];
#pragma unroll
        for (int i = 1; i < SS; i++) m = fmaxf(m, sc[i]);
        float e[SS], ssum = 0.f;
#pragma unroll
        for (int i = 0; i < SS; i++) { e[i] = __expf(sc[i] - m); ssum += e[i]; }
        const float inv = 1.f / ssum;
#pragma unroll
        for (int i = 0; i < SS; i++) wbuf[nb][j * SS + i] = e[i] * inv;
    }
    __syncthreads();

    // out[b][j][t] = silu( (sum_i w[j][i]*vp[i][t]) * sp[j][t] )
#pragma unroll
    for (int nb = 0; nb < NB; nb++) {
        const size_t obase = (size_t)(b0 + nb) * SS * VSA + 4 * tid;
#pragma unroll
        for (int j = 0; j < SS; j++) {
            float wj[SS];
#pragma unroll
            for (int i = 0; i < SS; i++) wj[i] = wbuf[nb][j * SS + i];  // LDS broadcast
            float att[4] = {0.f, 0.f, 0.f, 0.f};
#pragma unroll
            for (int i = 0; i < SS; i++) {
                const float wi = wj[i];
#pragma unroll
                for (int e = 0; e < 4; e++) att[e] += wi * vp[nb][i][e];
            }
            v4f o;
            o.x = silu_f(att[0] * sp4[j][0]);
            o.y = silu_f(att[1] * sp4[j][1]);
            o.z = silu_f(att[2] * sp4[j][2]);
            o.w = silu_f(att[3] * sp4[j][3]);
            __builtin_nontemporal_store(o, (v4f*)&out[obase + (size_t)j * VSA]);
        }
    }
}

extern "C" void kernel_launch(void* const* d_in, const int* in_sizes, int n_in,
                              void* d_out, int out_size, void* d_ws, size_t ws_size,
                              hipStream_t stream) {
    const float* values  = (const float*)d_in[0];
    const float* h       = (const float*)d_in[1];
    const float* symbols = (const float*)d_in[2];
    const float* gamma   = (const float*)d_in[3];
    const float* beta    = (const float*)d_in[4];
    float* out   = (float*)d_out;
    float* sp    = (float*)d_ws;                 // 5*1024 floats
    float* hpadG = (float*)d_ws + SS * VSA;      // 5*1092 floats (padded h)

    sp_kernel<<<SS, NT, 0, stream>>>(symbols, h, gamma, beta, sp, hpadG);
    main_kernel<<<BB / NB, NT, 0, stream>>>(values, hpadG, sp, gamma, beta, out);
}